// Round 16
// baseline (791.916 us; speedup 1.0000x reference)
//
#include <hip/hip_runtime.h>
#include <cstddef>
#include <cstdint>

constexpr int Vv = 32000, Dd = 512, Ss = 1024, Bb = 2, Hh = 8, DHd = 64, FFf = 2048;
constexpr int Tt = Bb * Ss;            // 2048 token rows
constexpr int QKVW = 3 * Dd;           // 1536 fused qkv width
constexpr float EPSf = 1e-5f;

typedef unsigned short ushort_t;
typedef short bf16x8 __attribute__((ext_vector_type(8)));
typedef float f32x4 __attribute__((ext_vector_type(4)));

// BT arena element offsets (all bf16)
constexpr size_t AQKV = 0;                    // 6 x [1536][512]
constexpr size_t AUO  = 4718592;              // 6 x [512][512]
constexpr size_t AFF1 = 6291456;              // 4 x [2048][512]
constexpr size_t AFF2 = 10485760;             // 4 x [512][2048]
constexpr size_t AEND = 14680064;             // 29.4 MB

__device__ __forceinline__ ushort_t f2b(float f) {
  unsigned int u = __float_as_uint(f);
  unsigned int r = (u + 0x7FFFu + ((u >> 16) & 1u)) >> 16;   // round-to-nearest-even
  return (ushort_t)r;
}
__device__ __forceinline__ float bits2f(ushort_t u) {
  return __uint_as_float((unsigned int)u << 16);
}

__device__ __forceinline__ void gload_lds16(const void* g, void* l) {
  __builtin_amdgcn_global_load_lds(
      (const __attribute__((address_space(1))) unsigned int*)g,
      (__attribute__((address_space(3))) unsigned int*)l, 16, 0, 0);
}

// ---------- batched prep: all weight transposes + embed (+ head tcast) -----
__global__ __launch_bounds__(256) void prep_all_k(
    const float* __restrict__ ewq, const float* __restrict__ ewk, const float* __restrict__ ewv,
    const float* __restrict__ swq, const float* __restrict__ swk, const float* __restrict__ swv,
    const float* __restrict__ cwq, const float* __restrict__ cwk, const float* __restrict__ cwv,
    const float* __restrict__ euo, const float* __restrict__ suo, const float* __restrict__ cuo,
    const float* __restrict__ eff1, const float* __restrict__ dff1,
    const float* __restrict__ eff2, const float* __restrict__ dff2,
    ushort_t* __restrict__ arena,
    const int* __restrict__ tok, const float* __restrict__ emb,
    float* __restrict__ X, float* __restrict__ ENC,
    const float* __restrict__ headw, ushort_t* __restrict__ headDst) {
  int idx = blockIdx.x;

  if (idx >= 14336 && idx < 16384) {   // ---- embed + positional encoding
    int row = idx - 14336;
    int s = row & (Ss - 1);
    int t = tok[row];
    const float* e = emb + (size_t)t * Dd;
    for (int d = threadIdx.x; d < Dd; d += 256) {
      int i = d >> 1;
      float den = expf(-(float)(2 * i) * (9.210340371976184f / 512.0f));
      float ang = (float)s * den;
      float pe = (d & 1) ? cosf(ang) : sinf(ang);
      float v = e[d] + pe;
      X[(size_t)row * Dd + d] = v;
      ENC[(size_t)row * Dd + d] = v;
    }
    return;
  }

  const float* src;
  ushort_t* dst;
  int R, C, tile;
  if (idx < 4608) {                    // qkv: 6(gl) x 3(t) x 8(h) x 32 tiles
    tile = idx & 31;
    int rest = idx >> 5;
    int h = rest & 7; rest >>= 3;
    int t = rest % 3, gl = rest / 3;
    int g = gl >> 1, l = gl & 1;
    const float* bq = (g == 0) ? ewq : (g == 1) ? swq : cwq;
    const float* bk = (g == 0) ? ewk : (g == 1) ? swk : cwk;
    const float* bv = (g == 0) ? ewv : (g == 1) ? swv : cwv;
    const float* base = (t == 0) ? bq : (t == 1) ? bk : bv;
    src = base + (size_t)l * (Hh * Dd * DHd) + (size_t)h * (Dd * DHd);
    dst = arena + AQKV + (size_t)gl * (QKVW * Dd) + ((size_t)t * Dd + h * DHd) * Dd;
    R = 512; C = 64;
  } else if (idx < 6144) {             // uo: 6(gl) x 256 tiles of 512x512
    int i2 = idx - 4608;
    tile = i2 & 255;
    int gl = i2 >> 8;
    int g = gl >> 1, l = gl & 1;
    const float* base = (g == 0) ? euo : (g == 1) ? suo : cuo;
    src = base + (size_t)l * (Dd * Dd);
    dst = arena + AUO + (size_t)gl * (Dd * Dd);
    R = 512; C = 512;
  } else if (idx < 10240) {            // ff1: 4(dl) x 1024 tiles of 512x2048
    int i3 = idx - 6144;
    tile = i3 & 1023;
    int dl = i3 >> 10;
    int d = dl >> 1, l = dl & 1;
    src = (d ? dff1 : eff1) + (size_t)l * (Dd * FFf);
    dst = arena + AFF1 + (size_t)dl * (Dd * FFf);
    R = 512; C = 2048;
  } else if (idx < 14336) {            // ff2: 4(dl) x 1024 tiles of 2048x512
    int i4 = idx - 10240;
    tile = i4 & 1023;
    int dl = i4 >> 10;
    int d = dl >> 1, l = dl & 1;
    src = (d ? dff2 : eff2) + (size_t)l * (FFf * Dd);
    dst = arena + AFF2 + (size_t)dl * (FFf * Dd);
    R = 2048; C = 512;
  } else {                             // head: 16000 tiles of [512][32000]
    tile = idx - 16384;
    src = headw; dst = headDst;
    R = 512; C = 32000;
  }
  int nR = R >> 5;
  int r0 = (tile % nR) * 32, c0 = (tile / nR) * 32;
  __shared__ float tb[32][33];
  int tx = threadIdx.x & 31, ty = threadIdx.x >> 5;
#pragma unroll
  for (int i = 0; i < 4; i++)
    tb[ty + i * 8][tx] = src[(size_t)(r0 + ty + i * 8) * C + c0 + tx];
  __syncthreads();
#pragma unroll
  for (int i = 0; i < 4; i++)
    dst[(size_t)(c0 + ty + i * 8) * R + r0 + tx] = f2b(tb[tx][ty + i * 8]);
}

// --------------- LDS-tiled transpose-cast (head fallback path only)
__global__ __launch_bounds__(256) void tcast_k(const float* __restrict__ in,
                                               ushort_t* __restrict__ out,
                                               int R, int C) {
  __shared__ float t[32][33];
  int c0 = blockIdx.x * 32, r0 = blockIdx.y * 32;
  int tx = threadIdx.x & 31, ty = threadIdx.x >> 5;
#pragma unroll
  for (int i = 0; i < 4; i++)
    t[ty + i * 8][tx] = in[(size_t)(r0 + ty + i * 8) * C + c0 + tx];
  __syncthreads();
#pragma unroll
  for (int i = 0; i < 4; i++)
    out[(size_t)(c0 + ty + i * 8) * R + r0 + tx] = f2b(t[tx][ty + i * 8]);
}

// ---------------------------------------------- dual layernorm (f32 -> bf16)
__global__ __launch_bounds__(256) void ln2_k(const float* __restrict__ in0,
                                             const float* __restrict__ g0,
                                             const float* __restrict__ b0,
                                             ushort_t* __restrict__ o0,
                                             const float* __restrict__ in1,
                                             const float* __restrict__ g1,
                                             const float* __restrict__ b1,
                                             ushort_t* __restrict__ o1,
                                             int nblk0) {
  int row = blockIdx.x;
  const float* in = in0; const float* g = g0; const float* b = b0; ushort_t* out = o0;
  if (row >= nblk0) { row -= nblk0; in = in1; g = g1; b = b1; out = o1; }
  const float* x = in + (size_t)row * Dd;
  int tid = threadIdx.x;
  float v0 = x[tid], v1 = x[tid + 256];
  float s = v0 + v1, ss = v0 * v0 + v1 * v1;
  for (int o = 32; o; o >>= 1) {
    s  += __shfl_down(s, o, 64);
    ss += __shfl_down(ss, o, 64);
  }
  __shared__ float rs[4], rss[4];
  int wid = tid >> 6, lane = tid & 63;
  if (lane == 0) { rs[wid] = s; rss[wid] = ss; }
  __syncthreads();
  __shared__ float mean_s, inv_s;
  if (tid == 0) {
    float a = rs[0] + rs[1] + rs[2] + rs[3];
    float c = rss[0] + rss[1] + rss[2] + rss[3];
    float m = a / Dd;
    float var = c / Dd - m * m;
    mean_s = m;
    inv_s = rsqrtf(var + EPSf);
  }
  __syncthreads();
  float m = mean_s, inv = inv_s;
  out[(size_t)row * Dd + tid]       = f2b((v0 - m) * inv * g[tid]       + b[tid]);
  out[(size_t)row * Dd + tid + 256] = f2b((v1 - m) * inv * g[tid + 256] + b[tid + 256]);
}

// -------------------------------------------- common: XCD swizzle for GEMMs
__device__ __forceinline__ void block_coords(int o, int nwg, bool nmajor,
                                             int nbM, int nbN, int& bmOut, int& bnOut) {
  int q = nwg >> 3, r = nwg & 7;
  int x = o & 7, i = o >> 3;
  int l = (x < r ? x * (q + 1) : r * (q + 1) + (x - r) * q) + i;
  int mb, nb;
  if (nmajor) { mb = l % nbM; nb = l / nbM; }
  else        { nb = l % nbN; mb = l / nbN; }
  bmOut = mb; bnOut = nb;
}

// ------------------------------------------ descriptor-based dual MFMA GEMM
// C[.][N](ldc) = A[.][K]bf16 * BT[N][K]bf16^T.
// Epilogue modes: f32 (+bias/resid/relu/bf16) or attn-split (amode=1):
// seg=(col>>9)+segoff: 0 -> Qhi/Qlo bf16, 1 -> Khi/Klo bf16, 2 -> V bf16.
// Single-buffered m97 schedule; occupancy > per-barrier-work (r9/r12).
struct GD {
  const ushort_t* A; const ushort_t* BT; const float* bias; const float* resid;
  void* C; int N; int K; int ldc; int nbM; int nbN; int nwg; int relu; int obf16;
  ushort_t* qh; ushort_t* ql; ushort_t* kh; ushort_t* kl; ushort_t* av;
  int amode; int segoff;
};

template <int BM, int BN, int BK, bool NMAJOR>
__global__ __launch_bounds__(256) void gemm2_k(GD d0, GD d1, int nblk0) {
  constexpr int FM = BM / 32, FN = BN / 32;
  constexpr int KG = BK / 8;                 // 8-elem col groups per row
  __shared__ __align__(16) ushort_t As[BM * BK];
  __shared__ __align__(16) ushort_t Bs[BN * BK];

  GD d = d0;
  int o = blockIdx.x;
  if (o >= nblk0) { d = d1; o -= nblk0; }
  int mb, nb;
  block_coords(o, d.nwg, NMAJOR, d.nbM, d.nbN, mb, nb);
  int bm = mb * BM, bn = nb * BN;
  int K = d.K, ldc = d.ldc;

  int tid = threadIdx.x;
  int lane = tid & 63, w = tid >> 6;
  int wr = w >> 1, wc = w & 1;
  f32x4 acc[FM][FN];
#pragma unroll
  for (int m = 0; m < FM; m++)
#pragma unroll
    for (int n = 0; n < FN; n++) acc[m][n] = (f32x4){0.f, 0.f, 0.f, 0.f};

  const ushort_t* aBase = d.A + (size_t)bm * K;
  const ushort_t* bBase = d.BT + (size_t)bn * K;
  int lr = lane & 15;
  int lk = (lane >> 4) * 8;

  for (int k0 = 0; k0 < K; k0 += BK) {
    __syncthreads();   // all waves done reading previous tile
#pragma unroll
    for (int it = 0; it < (BM * BK) / 2048; it++) {
      int cid = it * 256 + tid;
      int row = cid / KG, c8 = cid % KG;
      int sc8 = c8 ^ (row & 7);                 // inverse-swizzled source
      gload_lds16(aBase + (size_t)row * K + k0 + sc8 * 8, &As[cid * 8]);
    }
#pragma unroll
    for (int it = 0; it < (BN * BK) / 2048; it++) {
      int cid = it * 256 + tid;
      int row = cid / KG, c8 = cid % KG;
      int sc8 = c8 ^ (row & 7);
      gload_lds16(bBase + (size_t)row * K + k0 + sc8 * 8, &Bs[cid * 8]);
    }
    __syncthreads();   // staging visible (vmcnt(0) drained at barrier)
#pragma unroll
    for (int kk = 0; kk < BK; kk += 32) {
      bf16x8 af[FM], bfr[FN];
#pragma unroll
      for (int m = 0; m < FM; m++) {
        int row = wr * (BM / 2) + m * 16 + lr;
        af[m] = *(const bf16x8*)&As[row * BK + ((kk + lk) ^ ((row & 7) << 3))];
      }
#pragma unroll
      for (int n = 0; n < FN; n++) {
        int row = wc * (BN / 2) + n * 16 + lr;
        bfr[n] = *(const bf16x8*)&Bs[row * BK + ((kk + lk) ^ ((row & 7) << 3))];
      }
#pragma unroll
      for (int m = 0; m < FM; m++)
#pragma unroll
        for (int n = 0; n < FN; n++)
          acc[m][n] = __builtin_amdgcn_mfma_f32_16x16x32_bf16(af[m], bfr[n], acc[m][n], 0, 0, 0);
    }
  }

  int rowg = (lane >> 4) * 4;
#pragma unroll
  for (int m = 0; m < FM; m++) {
    int row0 = bm + wr * (BM / 2) + m * 16 + rowg;
#pragma unroll
    for (int n = 0; n < FN; n++) {
      int col = bn + wc * (BN / 2) + n * 16 + lr;
      float bv = d.bias ? d.bias[col] : 0.0f;
#pragma unroll
      for (int rr = 0; rr < 4; rr++) {
        int row = row0 + rr;
        float v = acc[m][n][rr] + bv;
        if (d.amode) {
          int seg = (col >> 9) + d.segoff;
          int cc = col & 511;
          size_t idx = (size_t)row * Dd + cc;
          ushort_t hi = f2b(v);
          if (seg >= 2) {
            d.av[idx] = hi;
          } else {
            ushort_t lo = f2b(v - bits2f(hi));
            if (seg == 1) { d.kh[idx] = hi; d.kl[idx] = lo; }
            else          { d.qh[idx] = hi; d.ql[idx] = lo; }
          }
        } else {
          if (d.resid) v += d.resid[(size_t)row * ldc + col];
          if (d.relu)  v = fmaxf(v, 0.0f);
          if (d.obf16) ((ushort_t*)d.C)[(size_t)row * ldc + col] = f2b(v);
          else         ((float*)d.C)[(size_t)row * ldc + col] = v;
        }
      }
    }
  }
}

// ------------------- barrier-free register-streaming GEMM (head, K=512)
// Fragments loaded straight from global (A, B both L2-resident at this
// shape); no LDS, no __syncthreads -> compiler pipelines the K-loop freely.
// Accumulation order identical to gemm2_k -> bit-identical output.
template <int BM, int BN>
__global__ __launch_bounds__(256) void gemm_reg_k(const ushort_t* __restrict__ A,
                                                  const ushort_t* __restrict__ BT,
                                                  const float* __restrict__ bias,
                                                  float* __restrict__ C,
                                                  int K, int ldc, int nbM, int nbN) {
  constexpr int FM = BM / 32, FN = BN / 32;
  int mb, nb;
  block_coords(blockIdx.x, gridDim.x, true, nbM, nbN, mb, nb);
  int bm = mb * BM, bn = nb * BN;

  int tid = threadIdx.x;
  int lane = tid & 63, w = tid >> 6;
  int wr = w >> 1, wc = w & 1;
  int lr = lane & 15;
  int lk = (lane >> 4) * 8;

  f32x4 acc[FM][FN];
#pragma unroll
  for (int m = 0; m < FM; m++)
#pragma unroll
    for (int n = 0; n < FN; n++) acc[m][n] = (f32x4){0.f, 0.f, 0.f, 0.f};

  const ushort_t* aRow[FM];
  const ushort_t* bRow[FN];
#pragma unroll
  for (int m = 0; m < FM; m++)
    aRow[m] = A + (size_t)(bm + wr * (BM / 2) + m * 16 + lr) * K + lk;
#pragma unroll
  for (int n = 0; n < FN; n++)
    bRow[n] = BT + (size_t)(bn + wc * (BN / 2) + n * 16 + lr) * K + lk;

#pragma unroll 2
  for (int k0 = 0; k0 < K; k0 += 32) {
    bf16x8 af[FM], bfr[FN];
#pragma unroll
    for (int m = 0; m < FM; m++) af[m] = *(const bf16x8*)(aRow[m] + k0);
#pragma unroll
    for (int n = 0; n < FN; n++) bfr[n] = *(const bf16x8*)(bRow[n] + k0);
#pragma unroll
    for (int m = 0; m < FM; m++)
#pragma unroll
      for (int n = 0; n < FN; n++)
        acc[m][n] = __builtin_amdgcn_mfma_f32_16x16x32_bf16(af[m], bfr[n], acc[m][n], 0, 0, 0);
  }

  int rowg = (lane >> 4) * 4;
#pragma unroll
  for (int m = 0; m < FM; m++) {
    int row0 = bm + wr * (BM / 2) + m * 16 + rowg;
#pragma unroll
    for (int n = 0; n < FN; n++) {
      int col = bn + wc * (BN / 2) + n * 16 + lr;
      float bv = bias ? bias[col] : 0.0f;
#pragma unroll
      for (int rr = 0; rr < 4; rr++) {
        int row = row0 + rr;
        C[(size_t)row * ldc + col] = acc[m][n][rr] + bv;
      }
    }
  }
}

// --------------------------------------------------- dual fused flash attn
struct AB { const ushort_t *qh, *ql, *kh, *kl, *vb; };

__global__ __launch_bounds__(128) void fattn_k(AB a0, ushort_t* __restrict__ AO0,
                                               AB a1, ushort_t* __restrict__ AO1,
                                               int nblk0) {
  int bid = blockIdx.x;
  AB ab = a0; ushort_t* AO = AO0;
  if (bid >= nblk0) { bid -= nblk0; ab = a1; AO = AO1; }
  int i4 = bid >> 4;
  int qt = (i4 < 16) ? (31 - i4) : (i4 - 16);
  int h  = bid & 7;
  int b  = (bid >> 3) & 1;
  int q0 = qt * 32;
  int tid = threadIdx.x;
  int lane = tid & 63, w = tid >> 6;
  int g = lane >> 4, c = lane & 15;

  __shared__ __align__(16) ushort_t Qh[32 * 64], Ql[32 * 64];
  __shared__ __align__(16) ushort_t Kh[64 * 64], Kl[64 * 64];
  __shared__ __align__(16) ushort_t VT[64 * 64];
  __shared__ __align__(16) ushort_t Ps[2][16 * 64];

  {
    int row = tid >> 2, c0 = (tid & 3) * 16;
    size_t base = (size_t)(b * Ss + q0 + row) * Dd + h * DHd + c0;
#pragma unroll
    for (int j = 0; j < 2; j++) {
      int col = c0 + j * 8;
      int sc = col ^ ((row & 7) << 3);
      *(bf16x8*)&Qh[row * 64 + sc] = *(const bf16x8*)&ab.qh[base + j * 8];
      *(bf16x8*)&Ql[row * 64 + sc] = *(const bf16x8*)&ab.ql[base + j * 8];
    }
  }

  f32x4 Oa[4];
#pragma unroll
  for (int n = 0; n < 4; n++) Oa[n] = (f32x4){0.f, 0.f, 0.f, 0.f};
  float mrow[4] = {-INFINITY, -INFINITY, -INFINITY, -INFINITY};
  float lrow[4] = {0.f, 0.f, 0.f, 0.f};

  int nkv = (qt >> 1) + 1;
  for (int it = 0; it < nkv; it++) {
    int t0 = it * 64;
    __syncthreads();
    {
      int row = tid >> 1, c0 = (tid & 1) * 32;
      size_t base = (size_t)(b * Ss + t0 + row) * Dd + h * DHd + c0;
#pragma unroll
      for (int j = 0; j < 4; j++) {
        int col = c0 + j * 8;
        int sc = col ^ ((row & 7) << 3);
        *(bf16x8*)&Kh[row * 64 + sc] = *(const bf16x8*)&ab.kh[base + j * 8];
        *(bf16x8*)&Kl[row * 64 + sc] = *(const bf16x8*)&ab.kl[base + j * 8];
      }
#pragma unroll
      for (int j = 0; j < 4; j++) {
        bf16x8 vv = *(const bf16x8*)&ab.vb[base + j * 8];
        int e0 = c0 + j * 8;
#pragma unroll
        for (int i = 0; i < 8; i++) {
          int e = e0 + i;
          VT[e * 64 + (row ^ ((e & 7) << 3))] = (ushort_t)vv[i];
        }
      }
    }
    __syncthreads();

    int arow = w * 16 + c;
    int ksw0 = (0 + g * 8) ^ ((c & 7) << 3);
    int ksw1 = (32 + g * 8) ^ ((c & 7) << 3);
    bf16x8 qh0 = *(const bf16x8*)&Qh[arow * 64 + ksw0];
    bf16x8 qh1 = *(const bf16x8*)&Qh[arow * 64 + ksw1];
    bf16x8 ql0 = *(const bf16x8*)&Ql[arow * 64 + ksw0];
    bf16x8 ql1 = *(const bf16x8*)&Ql[arow * 64 + ksw1];

    f32x4 sfr[4];
    __builtin_amdgcn_s_setprio(1);
#pragma unroll
    for (int n = 0; n < 4; n++) {
      int brow = n * 16 + c;
      bf16x8 kh0 = *(const bf16x8*)&Kh[brow * 64 + ksw0];
      bf16x8 kh1 = *(const bf16x8*)&Kh[brow * 64 + ksw1];
      bf16x8 kl0 = *(const bf16x8*)&Kl[brow * 64 + ksw0];
      bf16x8 kl1 = *(const bf16x8*)&Kl[brow * 64 + ksw1];
      f32x4 a = (f32x4){0.f, 0.f, 0.f, 0.f};
      a = __builtin_amdgcn_mfma_f32_16x16x32_bf16(qh0, kl0, a, 0, 0, 0);
      a = __builtin_amdgcn_mfma_f32_16x16x32_bf16(qh1, kl1, a, 0, 0, 0);
      a = __builtin_amdgcn_mfma_f32_16x16x32_bf16(ql0, kh0, a, 0, 0, 0);
      a = __builtin_amdgcn_mfma_f32_16x16x32_bf16(ql1, kh1, a, 0, 0, 0);
      a = __builtin_amdgcn_mfma_f32_16x16x32_bf16(qh0, kh0, a, 0, 0, 0);
      a = __builtin_amdgcn_mfma_f32_16x16x32_bf16(qh1, kh1, a, 0, 0, 0);
      sfr[n] = a;
    }
    __builtin_amdgcn_s_setprio(0);

#pragma unroll
    for (int n = 0; n < 4; n++) {
#pragma unroll
      for (int rr = 0; rr < 4; rr++) sfr[n][rr] *= 8.0f;
    }
    if (it == nkv - 1) {
#pragma unroll
      for (int n = 0; n < 4; n++) {
        int t = t0 + n * 16 + c;
#pragma unroll
        for (int rr = 0; rr < 4; rr++) {
          int s = q0 + w * 16 + g * 4 + rr;
          if (t > s) sfr[n][rr] = -INFINITY;
        }
      }
    }

    float pnew[4], scold[4];
#pragma unroll
    for (int rr = 0; rr < 4; rr++) {
      float tm = fmaxf(fmaxf(sfr[0][rr], sfr[1][rr]), fmaxf(sfr[2][rr], sfr[3][rr]));
      tm = fmaxf(tm, __shfl_xor(tm, 1));
      tm = fmaxf(tm, __shfl_xor(tm, 2));
      tm = fmaxf(tm, __shfl_xor(tm, 4));
      tm = fmaxf(tm, __shfl_xor(tm, 8));
      float mn = fmaxf(mrow[rr], tm);
      scold[rr] = __expf(mrow[rr] - mn);
      mrow[rr] = mn;
      pnew[rr] = mn;
    }
#pragma unroll
    for (int n = 0; n < 4; n++) {
#pragma unroll
      for (int rr = 0; rr < 4; rr++) sfr[n][rr] = __expf(sfr[n][rr] - pnew[rr]);
    }
#pragma unroll
    for (int rr = 0; rr < 4; rr++) {
      float s = sfr[0][rr] + sfr[1][rr] + sfr[2][rr] + sfr[3][rr];
      s += __shfl_xor(s, 1);
      s += __shfl_xor(s, 2);
      s += __shfl_xor(s, 4);
      s += __shfl_xor(s, 8);
      lrow[rr] = lrow[rr] * scold[rr] + s;
    }

#pragma unroll
    for (int n = 0; n < 4; n++) {
#pragma unroll
      for (int rr = 0; rr < 4; rr++) {
        int prow = g * 4 + rr;
        Ps[w][prow * 64 + ((n * 16 + c) ^ ((prow & 7) << 3))] = f2b(sfr[n][rr]);
      }
    }

#pragma unroll
    for (int n = 0; n < 4; n++) {
#pragma unroll
      for (int rr = 0; rr < 4; rr++) Oa[n][rr] *= scold[rr];
    }

    bf16x8 pa0 = *(const bf16x8*)&Ps[w][c * 64 + ksw0];
    bf16x8 pa1 = *(const bf16x8*)&Ps[w][c * 64 + ksw1];
    __builtin_amdgcn_s_setprio(1);
#pragma unroll
    for (int n = 0; n < 4; n++) {
      int vrow = n * 16 + c;
      bf16x8 v0 = *(const bf16x8*)&VT[vrow * 64 + ksw0];
      bf16x8 v1 = *(const bf16x8*)&VT[vrow * 64 + ksw1];
      Oa[n] = __builtin_amdgcn_mfma_f32_16x16x32_bf16(pa0, v0, Oa[n], 0, 0, 0);
      Oa[n] = __builtin_amdgcn_mfma_f32_16x16x32_bf16(pa1, v1, Oa[n], 0, 0, 0);
    }
    __builtin_amdgcn_s_setprio(0);
  }

#pragma unroll
  for (int rr = 0; rr < 4; rr++) {
    float inv = 1.0f / lrow[rr];
    int row = b * Ss + q0 + w * 16 + g * 4 + rr;
#pragma unroll
    for (int n = 0; n < 4; n++) {
      AO[(size_t)row * Dd + h * DHd + n * 16 + c] = f2b(Oa[n][rr] * inv);
    }
  }
}

// ---------------------------------------------------------------- host side
static GD mkGD(const ushort_t* A, const ushort_t* BT, const float* bias,
               const float* resid, void* C, int M, int N, int K, int ldc,
               int BM, int BN, int relu, int obf16) {
  GD d{};
  d.A = A; d.BT = BT; d.bias = bias; d.resid = resid; d.C = C;
  d.N = N; d.K = K; d.ldc = ldc;
  d.nbM = M / BM; d.nbN = N / BN; d.nwg = d.nbM * d.nbN;
  d.relu = relu; d.obf16 = obf16;
  d.amode = 0; d.segoff = 0;
  return d;
}

struct ABuf { ushort_t *qh, *ql, *kh, *kl, *vb; };

static GD mkGDA(const ushort_t* A, const ushort_t* BT, int M, int N, int K,
                int BM, int BN, const ABuf& ab, int segoff) {
  GD d{};
  d.A = A; d.BT = BT; d.bias = nullptr; d.resid = nullptr; d.C = nullptr;
  d.N = N; d.K = K; d.ldc = Dd;
  d.nbM = M / BM; d.nbN = N / BN; d.nwg = d.nbM * d.nbN;
  d.relu = 0; d.obf16 = 0;
  d.qh = ab.qh; d.ql = ab.ql; d.kh = ab.kh; d.kl = ab.kl; d.av = ab.vb;
  d.amode = 1; d.segoff = segoff;
  return d;
}

template <int BM, int BN, int BK, bool NMAJOR>
static void gemm1(hipStream_t st, GD d) {
  gemm2_k<BM, BN, BK, NMAJOR><<<dim3(d.nwg), dim3(256), 0, st>>>(d, d, d.nwg);
}
template <int BM, int BN, int BK, bool NMAJOR>
static void gemm2(hipStream_t st, GD d0, GD d1) {
  gemm2_k<BM, BN, BK, NMAJOR><<<dim3(d0.nwg + d1.nwg), dim3(256), 0, st>>>(d0, d1, d0.nwg);
}

static AB mkAB(const ABuf& b) {
  AB a; a.qh = b.qh; a.ql = b.ql; a.kh = b.kh; a.kl = b.kl; a.vb = b.vb;
  return a;
}

extern "C" void kernel_launch(void* const* d_in, const int* in_sizes, int n_in,
                              void* d_out, int out_size, void* d_ws, size_t ws_size,
                              hipStream_t stream) {
  const int*   tokens    = (const int*)d_in[0];
  const float* emb       = (const float*)d_in[1];
  const float* enc_wq    = (const float*)d_in[2];
  const float* enc_wk    = (const float*)d_in[3];
  const float* enc_wv    = (const float*)d_in[4];
  const float* enc_uo_w  = (const float*)d_in[5];
  const float* enc_uo_b  = (const float*)d_in[6];
  const float* enc_ln1_g = (const float*)d_in[7];
  const float* enc_ln1_b = (const float*)d_in[8];
  const float* enc_ln2_g = (const float*)d_in[9];
  const float* enc_ln2_b = (const float*)d_in[10];
  const float* enc_ff_w1 = (const float*)d_in[11];
  const float* enc_ff_b1 = (const float*)d_in[12];
  const float* enc_ff_w2 = (const float*)d_in[13];
  const float* enc_ff_b2 = (const float*)d_in[14];
  const float* dec_sa_wq = (const float*)d_in[15];
  const float* dec_sa_wk = (const float*)d_in[16];
  const float* dec_sa_wv = (const float*)d_in[17];
  const float* dec_sa_uo_w = (const float*)d_in[18];
  const float* dec_sa_uo_b = (const float*)d_in[19];
  const float* dec_ca_wq = (const float*)d_in[20];
  const float* dec_ca_wk = (const float*)d_in[21];
  const float* dec_ca_wv = (const float*)d_in[22];
  const float* dec_ca_uo_w = (const float*)d_in[23];
  const float* dec_ca_uo_b = (const float*)d_in[24];
  const float* dec_ln1_g = (const float*)d_in[25];
  const float* dec_ln1_b = (const float*)d_in[26];
  const float* dec_ln2_g = (const float*)d_in[27];
  const float* dec_ln2_b = (const float*)d_in[28];
  const float* dec_ln3_g = (const float*)d_in[29];
  const float* dec_ln3_b = (const float*)d_in[30];
  const float* dec_ff_w1 = (const float*)d_in[31];
  const float* dec_ff_b1 = (const float*)d_in[32];
  const float* dec_ff_w2 = (const float*)d_in[33];
  const float* dec_ff_b2 = (const float*)d_in[34];
  const float* ln_enc_g  = (const float*)d_in[35];
  const float* ln_enc_b  = (const float*)d_in[36];
  const float* ln_dec_g  = (const float*)d_in[37];
  const float* ln_dec_b  = (const float*)d_in[38];
  const float* head_w    = (const float*)d_in[39];
  const float* head_b    = (const float*)d_in[40];
  float* out = (float*)d_out;

  char* ws = (char*)d_ws;
  size_t off = 0;
  auto alloc = [&](size_t bytes) {
    void* p = ws + off;
    off += (bytes + 255) & ~(size_t)255;
    return p;
  };
  ushort_t* Hb    = (ushort_t*)alloc((size_t)Tt * Dd * 2);
  ushort_t* Hb2   = (ushort_t*)alloc((size_t)Tt * Dd * 2);
  ushort_t* ENCFb = (ushort_t*)alloc((size_t)Tt * Dd * 2);
  float*    X     = (float*)alloc((size_t)Tt * Dd * 4);
  float*    ENC   = (float*)alloc((size_t)Tt * Dd * 4);
  ABuf S1, S2;
  S1.qh = (ushort_t*)alloc((size_t)Tt * Dd * 2);
  S1.ql = (ushort_t*)alloc((size_t)Tt * Dd * 2);
  S1.kh = (ushort_t*)alloc((size_t)Tt * Dd * 2);
  S1.kl = (ushort_t*)alloc((size_t)Tt * Dd * 2);
  S1.vb = (ushort_t*)alloc((size_t)Tt * Dd * 2);
  S2.qh = (ushort_t*)alloc((size_t)Tt * Dd * 2);
  S2.ql = (ushort_t*)alloc((size_t)Tt * Dd * 2);
  S2.kh = (ushort_t*)alloc((size_t)Tt * Dd * 2);
  S2.kl = (ushort_t*)alloc((size_t)Tt * Dd * 2);
  S2.vb = (ushort_t*)alloc((size_t)Tt * Dd * 2);
  ushort_t* AO    = (ushort_t*)alloc((size_t)Tt * Dd * 2);
  ushort_t* AO2   = (ushort_t*)alloc((size_t)Tt * Dd * 2);
  ushort_t* Fb    = (ushort_t*)alloc((size_t)Tt * FFf * 2);
  ushort_t* ARENA = (ushort_t*)alloc(AEND * 2);              // 29.4 MB BT arena

  // head BT: dedicated region if workspace allows, else late overlay over X..
  size_t headBytes = (size_t)Vv * Dd * 2;
  bool headInPrep = (off + headBytes) <= ws_size;
  ushort_t* BThead = headInPrep ? (ushort_t*)alloc(headBytes) : (ushort_t*)X;

  dim3 blk(256), fblk(128);
  int attnB = Bb * Hh * (Ss / 32);   // 512

  // weight prep + embed (+ head tcast) in one launch
  {
    int nprep = 14336 + 2048 + (headInPrep ? 16000 : 0);
    prep_all_k<<<nprep, blk, 0, stream>>>(
        enc_wq, enc_wk, enc_wv, dec_sa_wq, dec_sa_wk, dec_sa_wv,
        dec_ca_wq, dec_ca_wk, dec_ca_wv,
        enc_uo_w, dec_sa_uo_w, dec_ca_uo_w,
        enc_ff_w1, dec_ff_w1, enc_ff_w2, dec_ff_w2, ARENA,
        tokens, emb, X, ENC, head_w, headInPrep ? BThead : nullptr);
  }

  auto BTq  = [&](int gl) { return ARENA + AQKV + (size_t)gl * (QKVW * Dd); };
  auto BTu  = [&](int gl) { return ARENA + AUO  + (size_t)gl * (Dd * Dd); };
  auto BT1  = [&](int dl) { return ARENA + AFF1 + (size_t)dl * (Dd * FFf); };
  auto BT2  = [&](int dl) { return ARENA + AFF2 + (size_t)dl * (FFf * Dd); };

  // ---- dual segment: enc L0 sa-path || dec L0 sa-path (both depend on embed)
  ln2_k<<<2 * Tt, blk, 0, stream>>>(ENC, enc_ln1_g, enc_ln1_b, Hb,
                                    X, dec_ln1_g, dec_ln1_b, Hb2, Tt);
  gemm2<64, 128, 128, true>(stream,
      mkGDA(Hb,  BTq(0), Tt, QKVW, Dd, 64, 128, S1, 0),
      mkGDA(Hb2, BTq(2), Tt, QKVW, Dd, 64, 128, S2, 0));
  fattn_k<<<2 * attnB, fblk, 0, stream>>>(mkAB(S1), AO, mkAB(S2), AO2, attnB);
  gemm2<64, 64, 128, true>(stream,
      mkGD(AO,  BTu(0), enc_uo_b,    ENC, ENC, Tt, Dd, Dd, Dd, 64, 64, 0, 0),
      mkGD(AO2, BTu(2), dec_sa_uo_b, X,   X,   Tt, Dd, Dd, Dd, 64, 64, 0, 0));
  // enc L0 LN2 || dec L0 LN2 (dec cross-Q needs only LN2(X))
  ln2_k<<<2 * Tt, blk, 0, stream>>>(ENC, enc_ln2_g, enc_ln2_b, Hb,
                                    X, dec_ln2_g, dec_ln2_b, Hb2, Tt);
  // enc L0 FF1 || dec L0 cross-Q (S2 sa-content dead after dual attn)
  gemm2<64, 128, 128, true>(stream,
      mkGD(Hb, BT1(0), enc_ff_b1, nullptr, Fb, Tt, FFf, Dd, FFf, 64, 128, 1, 1),
      mkGDA(Hb2, BTq(4), Tt, Dd, Dd, 64, 128, S2, 0));
  gemm1<64, 64, 128, false>(stream,
      mkGD(Fb, BT2(0), enc_ff_b2, ENC, ENC, Tt, Dd, FFf, Dd, 64, 64, 0, 0));

  // ---- enc L1 full
  ln2_k<<<Tt, blk, 0, stream>>>(ENC, enc_ln1_g + Dd, enc_ln1_b + Dd, Hb,
                                ENC, enc_ln1_g + Dd, enc_ln1_b + Dd, Hb, Tt);
  gemm1<64, 128, 128, true>(stream,
      mkGDA(Hb, BTq(1), Tt, QKVW, Dd, 64, 128, S1, 0));
  fattn_k<<<attnB, fblk, 0, stream>>>(mkAB(S1), AO, mkAB(S1), AO, attnB);
  gemm1<64, 64, 128, true>(stream,
      mkGD(AO, BTu(1), enc_uo_b + Dd, ENC, ENC, Tt, Dd, Dd, Dd, 64, 64, 0, 0));
  ln2_k<<<Tt, blk, 0, stream>>>(ENC, enc_ln2_g + Dd, enc_ln2_b + Dd, Hb,
                                ENC, enc_ln2_g + Dd, enc_ln2_b + Dd, Hb, Tt);
  gemm1<64, 128, 128, true>(stream,
      mkGD(Hb, BT1(1), enc_ff_b1 + FFf, nullptr, Fb, Tt, FFf, Dd, FFf, 64, 128, 1, 1));
  gemm1<64, 64, 128, false>(stream,
      mkGD(Fb, BT2(1), enc_ff_b2 + Dd, ENC, ENC, Tt, Dd, FFf, Dd, 64, 64, 0, 0));

  // ---- enc final LN, then dec L0 cross (Q already in S2.qh/ql)
  ln2_k<<<Tt, blk, 0, stream>>>(ENC, ln_enc_g, ln_enc_b, ENCFb,
                                ENC, ln_enc_g, ln_enc_b, ENCFb, Tt);
  gemm1<64, 128, 128, true>(stream,
      mkGDA(ENCFb, BTq(4) + (size_t)Dd * Dd, Tt, 2 * Dd, Dd, 64, 128, S2, 1));
  fattn_k<<<attnB, fblk, 0, stream>>>(mkAB(S2), AO2, mkAB(S2), AO2, attnB);
  gemm1<64, 64, 128, true>(stream,
      mkGD(AO2, BTu(4), dec_ca_uo_b, X, X, Tt, Dd, Dd, Dd, 64, 64, 0, 0));
  // dec L0 ffn
  ln2_k<<<Tt, blk, 0, stream>>>(X, dec_ln3_g, dec_ln3_b, Hb,
                                X, dec_ln3_g, dec_ln3_b, Hb, Tt);
  gemm1<64, 128, 128, true>(stream,
      mkGD(Hb, BT1(2), dec_ff_b1, nullptr, Fb, Tt, FFf, Dd, FFf, 64, 128, 1, 1));
  gemm1<64, 64, 128, false>(stream,
      mkGD(Fb, BT2(2), dec_ff_b2, X, X, Tt, Dd, FFf, Dd, 64, 64, 0, 0));

  // ---- dec L1
  ln2_k<<<Tt, blk, 0, stream>>>(X, dec_ln1_g + Dd, dec_ln1_b + Dd, Hb,
                                X, dec_ln1_g + Dd, dec_ln1_b + Dd, Hb, Tt);
  gemm1<64, 128, 128, true>(stream,
      mkGDA(Hb, BTq(3), Tt, QKVW, Dd, 64, 128, S1, 0));
  fattn_k<<<attnB, fblk, 0, stream>>>(mkAB(S1), AO, mkAB(S1), AO, attnB);
  gemm1<64, 64, 128, true>(stream,
      mkGD(AO, BTu(3), dec_sa_uo_b + Dd, X, X, Tt, Dd, Dd, Dd, 64, 64, 0, 0));
  ln2_k<<<Tt, blk, 0, stream>>>(X, dec_ln2_g + Dd, dec_ln2_b + Dd, Hb,
                                X, dec_ln2_g + Dd, dec_ln2_b + Dd, Hb, Tt);
  gemm2<64, 128, 128, true>(stream,
      mkGDA(Hb,    BTq(5),                   Tt, Dd,     Dd, 64, 128, S1, 0),
      mkGDA(ENCFb, BTq(5) + (size_t)Dd * Dd, Tt, 2 * Dd, Dd, 64, 128, S1, 1));
  fattn_k<<<attnB, fblk, 0, stream>>>(mkAB(S1), AO, mkAB(S1), AO, attnB);
  gemm1<64, 64, 128, true>(stream,
      mkGD(AO, BTu(5), dec_ca_uo_b + Dd, X, X, Tt, Dd, Dd, Dd, 64, 64, 0, 0));
  ln2_k<<<Tt, blk, 0, stream>>>(X, dec_ln3_g + Dd, dec_ln3_b + Dd, Hb,
                                X, dec_ln3_g + Dd, dec_ln3_b + Dd, Hb, Tt);
  gemm1<64, 128, 128, true>(stream,
      mkGD(Hb, BT1(3), dec_ff_b1 + FFf, nullptr, Fb, Tt, FFf, Dd, FFf, 64, 128, 1, 1));
  gemm1<64, 64, 128, false>(stream,
      mkGD(Fb, BT2(3), dec_ff_b2 + Dd, X, X, Tt, Dd, FFf, Dd, 64, 64, 0, 0));

  ln2_k<<<Tt, blk, 0, stream>>>(X, ln_dec_g, ln_dec_b, Hb, X, ln_dec_g, ln_dec_b, Hb, Tt);

  // vocab head: barrier-free register-streaming GEMM (128x128, no LDS)
  if (!headInPrep)
    tcast_k<<<dim3(Vv / 32, Dd / 32), blk, 0, stream>>>(head_w, BThead, Dd, Vv);
  {
    int nbM = Tt / 128, nbN = Vv / 128;
    gemm_reg_k<128, 128><<<dim3(nbM * nbN), blk, 0, stream>>>(
        Hb, BThead, head_b, out, Dd, Vv, nbM, nbN);
  }
}

// Round 17
// 680.964 us; speedup vs baseline: 1.1629x; 1.1629x over previous
//
#include <hip/hip_runtime.h>
#include <cstddef>
#include <cstdint>

constexpr int Vv = 32000, Dd = 512, Ss = 1024, Bb = 2, Hh = 8, DHd = 64, FFf = 2048;
constexpr int Tt = Bb * Ss;            // 2048 token rows
constexpr int QKVW = 3 * Dd;           // 1536 fused qkv width
constexpr float EPSf = 1e-5f;

typedef unsigned short ushort_t;
typedef short bf16x8 __attribute__((ext_vector_type(8)));
typedef float f32x4 __attribute__((ext_vector_type(4)));

// BT arena element offsets (all bf16)
constexpr size_t AQKV = 0;                    // 6 x [1536][512]
constexpr size_t AUO  = 4718592;              // 6 x [512][512]
constexpr size_t AFF1 = 6291456;              // 4 x [2048][512]
constexpr size_t AFF2 = 10485760;             // 4 x [512][2048]
constexpr size_t AEND = 14680064;             // 29.4 MB

__device__ __forceinline__ ushort_t f2b(float f) {
  unsigned int u = __float_as_uint(f);
  unsigned int r = (u + 0x7FFFu + ((u >> 16) & 1u)) >> 16;   // round-to-nearest-even
  return (ushort_t)r;
}
__device__ __forceinline__ float bits2f(ushort_t u) {
  return __uint_as_float((unsigned int)u << 16);
}

__device__ __forceinline__ void gload_lds16(const void* g, void* l) {
  __builtin_amdgcn_global_load_lds(
      (const __attribute__((address_space(1))) unsigned int*)g,
      (__attribute__((address_space(3))) unsigned int*)l, 16, 0, 0);
}

// ---------- batched prep: all weight transposes + embed (+ head tcast) -----
__global__ __launch_bounds__(256) void prep_all_k(
    const float* __restrict__ ewq, const float* __restrict__ ewk, const float* __restrict__ ewv,
    const float* __restrict__ swq, const float* __restrict__ swk, const float* __restrict__ swv,
    const float* __restrict__ cwq, const float* __restrict__ cwk, const float* __restrict__ cwv,
    const float* __restrict__ euo, const float* __restrict__ suo, const float* __restrict__ cuo,
    const float* __restrict__ eff1, const float* __restrict__ dff1,
    const float* __restrict__ eff2, const float* __restrict__ dff2,
    ushort_t* __restrict__ arena,
    const int* __restrict__ tok, const float* __restrict__ emb,
    float* __restrict__ X, float* __restrict__ ENC,
    const float* __restrict__ headw, ushort_t* __restrict__ headDst) {
  int idx = blockIdx.x;

  if (idx >= 14336 && idx < 16384) {   // ---- embed + positional encoding
    int row = idx - 14336;
    int s = row & (Ss - 1);
    int t = tok[row];
    const float* e = emb + (size_t)t * Dd;
    for (int d = threadIdx.x; d < Dd; d += 256) {
      int i = d >> 1;
      float den = expf(-(float)(2 * i) * (9.210340371976184f / 512.0f));
      float ang = (float)s * den;
      float pe = (d & 1) ? cosf(ang) : sinf(ang);
      float v = e[d] + pe;
      X[(size_t)row * Dd + d] = v;
      ENC[(size_t)row * Dd + d] = v;
    }
    return;
  }

  const float* src;
  ushort_t* dst;
  int R, C, tile;
  if (idx < 4608) {                    // qkv: 6(gl) x 3(t) x 8(h) x 32 tiles
    tile = idx & 31;
    int rest = idx >> 5;
    int h = rest & 7; rest >>= 3;
    int t = rest % 3, gl = rest / 3;
    int g = gl >> 1, l = gl & 1;
    const float* bq = (g == 0) ? ewq : (g == 1) ? swq : cwq;
    const float* bk = (g == 0) ? ewk : (g == 1) ? swk : cwk;
    const float* bv = (g == 0) ? ewv : (g == 1) ? swv : cwv;
    const float* base = (t == 0) ? bq : (t == 1) ? bk : bv;
    src = base + (size_t)l * (Hh * Dd * DHd) + (size_t)h * (Dd * DHd);
    dst = arena + AQKV + (size_t)gl * (QKVW * Dd) + ((size_t)t * Dd + h * DHd) * Dd;
    R = 512; C = 64;
  } else if (idx < 6144) {             // uo: 6(gl) x 256 tiles of 512x512
    int i2 = idx - 4608;
    tile = i2 & 255;
    int gl = i2 >> 8;
    int g = gl >> 1, l = gl & 1;
    const float* base = (g == 0) ? euo : (g == 1) ? suo : cuo;
    src = base + (size_t)l * (Dd * Dd);
    dst = arena + AUO + (size_t)gl * (Dd * Dd);
    R = 512; C = 512;
  } else if (idx < 10240) {            // ff1: 4(dl) x 1024 tiles of 512x2048
    int i3 = idx - 6144;
    tile = i3 & 1023;
    int dl = i3 >> 10;
    int d = dl >> 1, l = dl & 1;
    src = (d ? dff1 : eff1) + (size_t)l * (Dd * FFf);
    dst = arena + AFF1 + (size_t)dl * (Dd * FFf);
    R = 512; C = 2048;
  } else if (idx < 14336) {            // ff2: 4(dl) x 1024 tiles of 2048x512
    int i4 = idx - 10240;
    tile = i4 & 1023;
    int dl = i4 >> 10;
    int d = dl >> 1, l = dl & 1;
    src = (d ? dff2 : eff2) + (size_t)l * (FFf * Dd);
    dst = arena + AFF2 + (size_t)dl * (FFf * Dd);
    R = 2048; C = 512;
  } else {                             // head: 16000 tiles of [512][32000]
    tile = idx - 16384;
    src = headw; dst = headDst;
    R = 512; C = 32000;
  }
  int nR = R >> 5;
  int r0 = (tile % nR) * 32, c0 = (tile / nR) * 32;
  __shared__ float tb[32][33];
  int tx = threadIdx.x & 31, ty = threadIdx.x >> 5;
#pragma unroll
  for (int i = 0; i < 4; i++)
    tb[ty + i * 8][tx] = src[(size_t)(r0 + ty + i * 8) * C + c0 + tx];
  __syncthreads();
#pragma unroll
  for (int i = 0; i < 4; i++)
    dst[(size_t)(c0 + ty + i * 8) * R + r0 + tx] = f2b(tb[tx][ty + i * 8]);
}

// --------------- LDS-tiled transpose-cast (head fallback path only)
__global__ __launch_bounds__(256) void tcast_k(const float* __restrict__ in,
                                               ushort_t* __restrict__ out,
                                               int R, int C) {
  __shared__ float t[32][33];
  int c0 = blockIdx.x * 32, r0 = blockIdx.y * 32;
  int tx = threadIdx.x & 31, ty = threadIdx.x >> 5;
#pragma unroll
  for (int i = 0; i < 4; i++)
    t[ty + i * 8][tx] = in[(size_t)(r0 + ty + i * 8) * C + c0 + tx];
  __syncthreads();
#pragma unroll
  for (int i = 0; i < 4; i++)
    out[(size_t)(c0 + ty + i * 8) * R + r0 + tx] = f2b(t[tx][ty + i * 8]);
}

// ---------------------------------------------- dual layernorm (f32 -> bf16)
__global__ __launch_bounds__(256) void ln2_k(const float* __restrict__ in0,
                                             const float* __restrict__ g0,
                                             const float* __restrict__ b0,
                                             ushort_t* __restrict__ o0,
                                             const float* __restrict__ in1,
                                             const float* __restrict__ g1,
                                             const float* __restrict__ b1,
                                             ushort_t* __restrict__ o1,
                                             int nblk0) {
  int row = blockIdx.x;
  const float* in = in0; const float* g = g0; const float* b = b0; ushort_t* out = o0;
  if (row >= nblk0) { row -= nblk0; in = in1; g = g1; b = b1; out = o1; }
  const float* x = in + (size_t)row * Dd;
  int tid = threadIdx.x;
  float v0 = x[tid], v1 = x[tid + 256];
  float s = v0 + v1, ss = v0 * v0 + v1 * v1;
  for (int o = 32; o; o >>= 1) {
    s  += __shfl_down(s, o, 64);
    ss += __shfl_down(ss, o, 64);
  }
  __shared__ float rs[4], rss[4];
  int wid = tid >> 6, lane = tid & 63;
  if (lane == 0) { rs[wid] = s; rss[wid] = ss; }
  __syncthreads();
  __shared__ float mean_s, inv_s;
  if (tid == 0) {
    float a = rs[0] + rs[1] + rs[2] + rs[3];
    float c = rss[0] + rss[1] + rss[2] + rss[3];
    float m = a / Dd;
    float var = c / Dd - m * m;
    mean_s = m;
    inv_s = rsqrtf(var + EPSf);
  }
  __syncthreads();
  float m = mean_s, inv = inv_s;
  out[(size_t)row * Dd + tid]       = f2b((v0 - m) * inv * g[tid]       + b[tid]);
  out[(size_t)row * Dd + tid + 256] = f2b((v1 - m) * inv * g[tid + 256] + b[tid + 256]);
}

// -------------------------------------------- common: XCD swizzle for GEMMs
__device__ __forceinline__ void block_coords(int o, int nwg, bool nmajor,
                                             int nbM, int nbN, int& bmOut, int& bnOut) {
  int q = nwg >> 3, r = nwg & 7;
  int x = o & 7, i = o >> 3;
  int l = (x < r ? x * (q + 1) : r * (q + 1) + (x - r) * q) + i;
  int mb, nb;
  if (nmajor) { mb = l % nbM; nb = l / nbM; }
  else        { nb = l % nbN; mb = l / nbN; }
  bmOut = mb; bnOut = nb;
}

// ------------------------------------------ descriptor-based dual MFMA GEMM
// C[.][N](ldc) = A[.][K]bf16 * BT[N][K]bf16^T.
// Epilogue modes: f32 (+bias/resid/relu/bf16) or attn-split (amode=1):
// seg=(col>>9)+segoff: 0 -> Qhi/Qlo bf16, 1 -> Khi/Klo bf16, 2 -> V bf16.
// Single-buffered m97 schedule; occupancy > per-barrier-work (r9/r12/r15/r16).
struct GD {
  const ushort_t* A; const ushort_t* BT; const float* bias; const float* resid;
  void* C; int N; int K; int ldc; int nbM; int nbN; int nwg; int relu; int obf16;
  ushort_t* qh; ushort_t* ql; ushort_t* kh; ushort_t* kl; ushort_t* av;
  int amode; int segoff;
};

template <int BM, int BN, int BK, bool NMAJOR>
__global__ __launch_bounds__(256) void gemm2_k(GD d0, GD d1, int nblk0) {
  constexpr int FM = BM / 32, FN = BN / 32;
  constexpr int KG = BK / 8;                 // 8-elem col groups per row
  __shared__ __align__(16) ushort_t As[BM * BK];
  __shared__ __align__(16) ushort_t Bs[BN * BK];

  GD d = d0;
  int o = blockIdx.x;
  if (o >= nblk0) { d = d1; o -= nblk0; }
  int mb, nb;
  block_coords(o, d.nwg, NMAJOR, d.nbM, d.nbN, mb, nb);
  int bm = mb * BM, bn = nb * BN;
  int K = d.K, ldc = d.ldc;

  int tid = threadIdx.x;
  int lane = tid & 63, w = tid >> 6;
  int wr = w >> 1, wc = w & 1;
  f32x4 acc[FM][FN];
#pragma unroll
  for (int m = 0; m < FM; m++)
#pragma unroll
    for (int n = 0; n < FN; n++) acc[m][n] = (f32x4){0.f, 0.f, 0.f, 0.f};

  const ushort_t* aBase = d.A + (size_t)bm * K;
  const ushort_t* bBase = d.BT + (size_t)bn * K;
  int lr = lane & 15;
  int lk = (lane >> 4) * 8;

  for (int k0 = 0; k0 < K; k0 += BK) {
    __syncthreads();   // all waves done reading previous tile
#pragma unroll
    for (int it = 0; it < (BM * BK) / 2048; it++) {
      int cid = it * 256 + tid;
      int row = cid / KG, c8 = cid % KG;
      int sc8 = c8 ^ (row & 7);                 // inverse-swizzled source
      gload_lds16(aBase + (size_t)row * K + k0 + sc8 * 8, &As[cid * 8]);
    }
#pragma unroll
    for (int it = 0; it < (BN * BK) / 2048; it++) {
      int cid = it * 256 + tid;
      int row = cid / KG, c8 = cid % KG;
      int sc8 = c8 ^ (row & 7);
      gload_lds16(bBase + (size_t)row * K + k0 + sc8 * 8, &Bs[cid * 8]);
    }
    __syncthreads();   // staging visible (vmcnt(0) drained at barrier)
#pragma unroll
    for (int kk = 0; kk < BK; kk += 32) {
      bf16x8 af[FM], bfr[FN];
#pragma unroll
      for (int m = 0; m < FM; m++) {
        int row = wr * (BM / 2) + m * 16 + lr;
        af[m] = *(const bf16x8*)&As[row * BK + ((kk + lk) ^ ((row & 7) << 3))];
      }
#pragma unroll
      for (int n = 0; n < FN; n++) {
        int row = wc * (BN / 2) + n * 16 + lr;
        bfr[n] = *(const bf16x8*)&Bs[row * BK + ((kk + lk) ^ ((row & 7) << 3))];
      }
#pragma unroll
      for (int m = 0; m < FM; m++)
#pragma unroll
        for (int n = 0; n < FN; n++)
          acc[m][n] = __builtin_amdgcn_mfma_f32_16x16x32_bf16(af[m], bfr[n], acc[m][n], 0, 0, 0);
    }
  }

  int rowg = (lane >> 4) * 4;
#pragma unroll
  for (int m = 0; m < FM; m++) {
    int row0 = bm + wr * (BM / 2) + m * 16 + rowg;
#pragma unroll
    for (int n = 0; n < FN; n++) {
      int col = bn + wc * (BN / 2) + n * 16 + lr;
      float bv = d.bias ? d.bias[col] : 0.0f;
#pragma unroll
      for (int rr = 0; rr < 4; rr++) {
        int row = row0 + rr;
        float v = acc[m][n][rr] + bv;
        if (d.amode) {
          int seg = (col >> 9) + d.segoff;
          int cc = col & 511;
          size_t idx = (size_t)row * Dd + cc;
          ushort_t hi = f2b(v);
          if (seg >= 2) {
            d.av[idx] = hi;
          } else {
            ushort_t lo = f2b(v - bits2f(hi));
            if (seg == 1) { d.kh[idx] = hi; d.kl[idx] = lo; }
            else          { d.qh[idx] = hi; d.ql[idx] = lo; }
          }
        } else {
          if (d.resid) v += d.resid[(size_t)row * ldc + col];
          if (d.relu)  v = fmaxf(v, 0.0f);
          if (d.obf16) ((ushort_t*)d.C)[(size_t)row * ldc + col] = f2b(v);
          else         ((float*)d.C)[(size_t)row * ldc + col] = v;
        }
      }
    }
  }
}

// --------------------------------------------------- dual fused flash attn
// Operands arrive pre-split (Qh/Ql/Kh/Kl bf16-hi/lo, V bf16) -> staging is
// pure vector loads + swizzled LDS stores, no per-element VALU conversion.
struct AB { const ushort_t *qh, *ql, *kh, *kl, *vb; };

__global__ __launch_bounds__(128) void fattn_k(AB a0, ushort_t* __restrict__ AO0,
                                               AB a1, ushort_t* __restrict__ AO1,
                                               int nblk0) {
  int bid = blockIdx.x;
  AB ab = a0; ushort_t* AO = AO0;
  if (bid >= nblk0) { bid -= nblk0; ab = a1; AO = AO1; }
  int i4 = bid >> 4;
  int qt = (i4 < 16) ? (31 - i4) : (i4 - 16);
  int h  = bid & 7;
  int b  = (bid >> 3) & 1;
  int q0 = qt * 32;
  int tid = threadIdx.x;
  int lane = tid & 63, w = tid >> 6;
  int g = lane >> 4, c = lane & 15;

  __shared__ __align__(16) ushort_t Qh[32 * 64], Ql[32 * 64];
  __shared__ __align__(16) ushort_t Kh[64 * 64], Kl[64 * 64];
  __shared__ __align__(16) ushort_t VT[64 * 64];
  __shared__ __align__(16) ushort_t Ps[2][16 * 64];

  // ---- stage Q (pre-split): row = tid>>2 (0..31), cols (tid&3)*16..+16
  {
    int row = tid >> 2, c0 = (tid & 3) * 16;
    size_t base = (size_t)(b * Ss + q0 + row) * Dd + h * DHd + c0;
#pragma unroll
    for (int j = 0; j < 2; j++) {
      int col = c0 + j * 8;
      int sc = col ^ ((row & 7) << 3);
      *(bf16x8*)&Qh[row * 64 + sc] = *(const bf16x8*)&ab.qh[base + j * 8];
      *(bf16x8*)&Ql[row * 64 + sc] = *(const bf16x8*)&ab.ql[base + j * 8];
    }
  }

  f32x4 Oa[4];
#pragma unroll
  for (int n = 0; n < 4; n++) Oa[n] = (f32x4){0.f, 0.f, 0.f, 0.f};
  float mrow[4] = {-INFINITY, -INFINITY, -INFINITY, -INFINITY};
  float lrow[4] = {0.f, 0.f, 0.f, 0.f};

  int nkv = (qt >> 1) + 1;
  for (int it = 0; it < nkv; it++) {
    int t0 = it * 64;
    __syncthreads();
    // ---- stage K (pre-split) + V^T: row = tid>>1 (0..63), cols (tid&1)*32..+32
    {
      int row = tid >> 1, c0 = (tid & 1) * 32;
      size_t base = (size_t)(b * Ss + t0 + row) * Dd + h * DHd + c0;
#pragma unroll
      for (int j = 0; j < 4; j++) {
        int col = c0 + j * 8;
        int sc = col ^ ((row & 7) << 3);
        *(bf16x8*)&Kh[row * 64 + sc] = *(const bf16x8*)&ab.kh[base + j * 8];
        *(bf16x8*)&Kl[row * 64 + sc] = *(const bf16x8*)&ab.kl[base + j * 8];
      }
#pragma unroll
      for (int j = 0; j < 4; j++) {
        bf16x8 vv = *(const bf16x8*)&ab.vb[base + j * 8];
        int e0 = c0 + j * 8;
#pragma unroll
        for (int i = 0; i < 8; i++) {
          int e = e0 + i;
          VT[e * 64 + (row ^ ((e & 7) << 3))] = (ushort_t)vv[i];
        }
      }
    }
    __syncthreads();

    int arow = w * 16 + c;
    int ksw0 = (0 + g * 8) ^ ((c & 7) << 3);
    int ksw1 = (32 + g * 8) ^ ((c & 7) << 3);
    bf16x8 qh0 = *(const bf16x8*)&Qh[arow * 64 + ksw0];
    bf16x8 qh1 = *(const bf16x8*)&Qh[arow * 64 + ksw1];
    bf16x8 ql0 = *(const bf16x8*)&Ql[arow * 64 + ksw0];
    bf16x8 ql1 = *(const bf16x8*)&Ql[arow * 64 + ksw1];

    f32x4 sfr[4];
    __builtin_amdgcn_s_setprio(1);
#pragma unroll
    for (int n = 0; n < 4; n++) {
      int brow = n * 16 + c;
      bf16x8 kh0 = *(const bf16x8*)&Kh[brow * 64 + ksw0];
      bf16x8 kh1 = *(const bf16x8*)&Kh[brow * 64 + ksw1];
      bf16x8 kl0 = *(const bf16x8*)&Kl[brow * 64 + ksw0];
      bf16x8 kl1 = *(const bf16x8*)&Kl[brow * 64 + ksw1];
      f32x4 a = (f32x4){0.f, 0.f, 0.f, 0.f};
      a = __builtin_amdgcn_mfma_f32_16x16x32_bf16(qh0, kl0, a, 0, 0, 0);
      a = __builtin_amdgcn_mfma_f32_16x16x32_bf16(qh1, kl1, a, 0, 0, 0);
      a = __builtin_amdgcn_mfma_f32_16x16x32_bf16(ql0, kh0, a, 0, 0, 0);
      a = __builtin_amdgcn_mfma_f32_16x16x32_bf16(ql1, kh1, a, 0, 0, 0);
      a = __builtin_amdgcn_mfma_f32_16x16x32_bf16(qh0, kh0, a, 0, 0, 0);
      a = __builtin_amdgcn_mfma_f32_16x16x32_bf16(qh1, kh1, a, 0, 0, 0);
      sfr[n] = a;
    }
    __builtin_amdgcn_s_setprio(0);

#pragma unroll
    for (int n = 0; n < 4; n++) {
#pragma unroll
      for (int rr = 0; rr < 4; rr++) sfr[n][rr] *= 8.0f;
    }
    if (it == nkv - 1) {
#pragma unroll
      for (int n = 0; n < 4; n++) {
        int t = t0 + n * 16 + c;
#pragma unroll
        for (int rr = 0; rr < 4; rr++) {
          int s = q0 + w * 16 + g * 4 + rr;
          if (t > s) sfr[n][rr] = -INFINITY;
        }
      }
    }

    float pnew[4], scold[4];
#pragma unroll
    for (int rr = 0; rr < 4; rr++) {
      float tm = fmaxf(fmaxf(sfr[0][rr], sfr[1][rr]), fmaxf(sfr[2][rr], sfr[3][rr]));
      tm = fmaxf(tm, __shfl_xor(tm, 1));
      tm = fmaxf(tm, __shfl_xor(tm, 2));
      tm = fmaxf(tm, __shfl_xor(tm, 4));
      tm = fmaxf(tm, __shfl_xor(tm, 8));
      float mn = fmaxf(mrow[rr], tm);
      scold[rr] = __expf(mrow[rr] - mn);
      mrow[rr] = mn;
      pnew[rr] = mn;
    }
#pragma unroll
    for (int n = 0; n < 4; n++) {
#pragma unroll
      for (int rr = 0; rr < 4; rr++) sfr[n][rr] = __expf(sfr[n][rr] - pnew[rr]);
    }
#pragma unroll
    for (int rr = 0; rr < 4; rr++) {
      float s = sfr[0][rr] + sfr[1][rr] + sfr[2][rr] + sfr[3][rr];
      s += __shfl_xor(s, 1);
      s += __shfl_xor(s, 2);
      s += __shfl_xor(s, 4);
      s += __shfl_xor(s, 8);
      lrow[rr] = lrow[rr] * scold[rr] + s;
    }

#pragma unroll
    for (int n = 0; n < 4; n++) {
#pragma unroll
      for (int rr = 0; rr < 4; rr++) {
        int prow = g * 4 + rr;
        Ps[w][prow * 64 + ((n * 16 + c) ^ ((prow & 7) << 3))] = f2b(sfr[n][rr]);
      }
    }

#pragma unroll
    for (int n = 0; n < 4; n++) {
#pragma unroll
      for (int rr = 0; rr < 4; rr++) Oa[n][rr] *= scold[rr];
    }

    bf16x8 pa0 = *(const bf16x8*)&Ps[w][c * 64 + ksw0];
    bf16x8 pa1 = *(const bf16x8*)&Ps[w][c * 64 + ksw1];
    __builtin_amdgcn_s_setprio(1);
#pragma unroll
    for (int n = 0; n < 4; n++) {
      int vrow = n * 16 + c;
      bf16x8 v0 = *(const bf16x8*)&VT[vrow * 64 + ksw0];
      bf16x8 v1 = *(const bf16x8*)&VT[vrow * 64 + ksw1];
      Oa[n] = __builtin_amdgcn_mfma_f32_16x16x32_bf16(pa0, v0, Oa[n], 0, 0, 0);
      Oa[n] = __builtin_amdgcn_mfma_f32_16x16x32_bf16(pa1, v1, Oa[n], 0, 0, 0);
    }
    __builtin_amdgcn_s_setprio(0);
  }

#pragma unroll
  for (int rr = 0; rr < 4; rr++) {
    float inv = 1.0f / lrow[rr];
    int row = b * Ss + q0 + w * 16 + g * 4 + rr;
#pragma unroll
    for (int n = 0; n < 4; n++) {
      AO[(size_t)row * Dd + h * DHd + n * 16 + c] = f2b(Oa[n][rr] * inv);
    }
  }
}

// ---------------------------------------------------------------- host side
static GD mkGD(const ushort_t* A, const ushort_t* BT, const float* bias,
               const float* resid, void* C, int M, int N, int K, int ldc,
               int BM, int BN, int relu, int obf16) {
  GD d{};
  d.A = A; d.BT = BT; d.bias = bias; d.resid = resid; d.C = C;
  d.N = N; d.K = K; d.ldc = ldc;
  d.nbM = M / BM; d.nbN = N / BN; d.nwg = d.nbM * d.nbN;
  d.relu = relu; d.obf16 = obf16;
  d.amode = 0; d.segoff = 0;
  return d;
}

struct ABuf { ushort_t *qh, *ql, *kh, *kl, *vb; };

static GD mkGDA(const ushort_t* A, const ushort_t* BT, int M, int N, int K,
                int BM, int BN, const ABuf& ab, int segoff) {
  GD d{};
  d.A = A; d.BT = BT; d.bias = nullptr; d.resid = nullptr; d.C = nullptr;
  d.N = N; d.K = K; d.ldc = Dd;
  d.nbM = M / BM; d.nbN = N / BN; d.nwg = d.nbM * d.nbN;
  d.relu = 0; d.obf16 = 0;
  d.qh = ab.qh; d.ql = ab.ql; d.kh = ab.kh; d.kl = ab.kl; d.av = ab.vb;
  d.amode = 1; d.segoff = segoff;
  return d;
}

template <int BM, int BN, int BK, bool NMAJOR>
static void gemm1(hipStream_t st, GD d) {
  gemm2_k<BM, BN, BK, NMAJOR><<<dim3(d.nwg), dim3(256), 0, st>>>(d, d, d.nwg);
}
template <int BM, int BN, int BK, bool NMAJOR>
static void gemm2(hipStream_t st, GD d0, GD d1) {
  gemm2_k<BM, BN, BK, NMAJOR><<<dim3(d0.nwg + d1.nwg), dim3(256), 0, st>>>(d0, d1, d0.nwg);
}

static AB mkAB(const ABuf& b) {
  AB a; a.qh = b.qh; a.ql = b.ql; a.kh = b.kh; a.kl = b.kl; a.vb = b.vb;
  return a;
}

extern "C" void kernel_launch(void* const* d_in, const int* in_sizes, int n_in,
                              void* d_out, int out_size, void* d_ws, size_t ws_size,
                              hipStream_t stream) {
  const int*   tokens    = (const int*)d_in[0];
  const float* emb       = (const float*)d_in[1];
  const float* enc_wq    = (const float*)d_in[2];
  const float* enc_wk    = (const float*)d_in[3];
  const float* enc_wv    = (const float*)d_in[4];
  const float* enc_uo_w  = (const float*)d_in[5];
  const float* enc_uo_b  = (const float*)d_in[6];
  const float* enc_ln1_g = (const float*)d_in[7];
  const float* enc_ln1_b = (const float*)d_in[8];
  const float* enc_ln2_g = (const float*)d_in[9];
  const float* enc_ln2_b = (const float*)d_in[10];
  const float* enc_ff_w1 = (const float*)d_in[11];
  const float* enc_ff_b1 = (const float*)d_in[12];
  const float* enc_ff_w2 = (const float*)d_in[13];
  const float* enc_ff_b2 = (const float*)d_in[14];
  const float* dec_sa_wq = (const float*)d_in[15];
  const float* dec_sa_wk = (const float*)d_in[16];
  const float* dec_sa_wv = (const float*)d_in[17];
  const float* dec_sa_uo_w = (const float*)d_in[18];
  const float* dec_sa_uo_b = (const float*)d_in[19];
  const float* dec_ca_wq = (const float*)d_in[20];
  const float* dec_ca_wk = (const float*)d_in[21];
  const float* dec_ca_wv = (const float*)d_in[22];
  const float* dec_ca_uo_w = (const float*)d_in[23];
  const float* dec_ca_uo_b = (const float*)d_in[24];
  const float* dec_ln1_g = (const float*)d_in[25];
  const float* dec_ln1_b = (const float*)d_in[26];
  const float* dec_ln2_g = (const float*)d_in[27];
  const float* dec_ln2_b = (const float*)d_in[28];
  const float* dec_ln3_g = (const float*)d_in[29];
  const float* dec_ln3_b = (const float*)d_in[30];
  const float* dec_ff_w1 = (const float*)d_in[31];
  const float* dec_ff_b1 = (const float*)d_in[32];
  const float* dec_ff_w2 = (const float*)d_in[33];
  const float* dec_ff_b2 = (const float*)d_in[34];
  const float* ln_enc_g  = (const float*)d_in[35];
  const float* ln_enc_b  = (const float*)d_in[36];
  const float* ln_dec_g  = (const float*)d_in[37];
  const float* ln_dec_b  = (const float*)d_in[38];
  const float* head_w    = (const float*)d_in[39];
  const float* head_b    = (const float*)d_in[40];
  float* out = (float*)d_out;

  char* ws = (char*)d_ws;
  size_t off = 0;
  auto alloc = [&](size_t bytes) {
    void* p = ws + off;
    off += (bytes + 255) & ~(size_t)255;
    return p;
  };
  ushort_t* Hb    = (ushort_t*)alloc((size_t)Tt * Dd * 2);
  ushort_t* Hb2   = (ushort_t*)alloc((size_t)Tt * Dd * 2);
  ushort_t* ENCFb = (ushort_t*)alloc((size_t)Tt * Dd * 2);
  float*    X     = (float*)alloc((size_t)Tt * Dd * 4);
  float*    ENC   = (float*)alloc((size_t)Tt * Dd * 4);
  ABuf S1, S2;
  S1.qh = (ushort_t*)alloc((size_t)Tt * Dd * 2);
  S1.ql = (ushort_t*)alloc((size_t)Tt * Dd * 2);
  S1.kh = (ushort_t*)alloc((size_t)Tt * Dd * 2);
  S1.kl = (ushort_t*)alloc((size_t)Tt * Dd * 2);
  S1.vb = (ushort_t*)alloc((size_t)Tt * Dd * 2);
  S2.qh = (ushort_t*)alloc((size_t)Tt * Dd * 2);
  S2.ql = (ushort_t*)alloc((size_t)Tt * Dd * 2);
  S2.kh = (ushort_t*)alloc((size_t)Tt * Dd * 2);
  S2.kl = (ushort_t*)alloc((size_t)Tt * Dd * 2);
  S2.vb = (ushort_t*)alloc((size_t)Tt * Dd * 2);
  ushort_t* AO    = (ushort_t*)alloc((size_t)Tt * Dd * 2);
  ushort_t* AO2   = (ushort_t*)alloc((size_t)Tt * Dd * 2);
  ushort_t* Fb    = (ushort_t*)alloc((size_t)Tt * FFf * 2);
  ushort_t* ARENA = (ushort_t*)alloc(AEND * 2);              // 29.4 MB BT arena

  // head BT: dedicated region if workspace allows, else late overlay over X..
  size_t headBytes = (size_t)Vv * Dd * 2;
  bool headInPrep = (off + headBytes) <= ws_size;
  ushort_t* BThead = headInPrep ? (ushort_t*)alloc(headBytes) : (ushort_t*)X;

  dim3 blk(256), fblk(128);
  int attnB = Bb * Hh * (Ss / 32);   // 512

  // weight prep + embed (+ head tcast) in one launch
  {
    int nprep = 14336 + 2048 + (headInPrep ? 16000 : 0);
    prep_all_k<<<nprep, blk, 0, stream>>>(
        enc_wq, enc_wk, enc_wv, dec_sa_wq, dec_sa_wk, dec_sa_wv,
        dec_ca_wq, dec_ca_wk, dec_ca_wv,
        enc_uo_w, dec_sa_uo_w, dec_ca_uo_w,
        enc_ff_w1, dec_ff_w1, enc_ff_w2, dec_ff_w2, ARENA,
        tokens, emb, X, ENC, head_w, headInPrep ? BThead : nullptr);
  }

  auto BTq  = [&](int gl) { return ARENA + AQKV + (size_t)gl * (QKVW * Dd); };
  auto BTu  = [&](int gl) { return ARENA + AUO  + (size_t)gl * (Dd * Dd); };
  auto BT1  = [&](int dl) { return ARENA + AFF1 + (size_t)dl * (Dd * FFf); };
  auto BT2  = [&](int dl) { return ARENA + AFF2 + (size_t)dl * (FFf * Dd); };

  // ---- dual segment: enc L0 sa-path || dec L0 sa-path (both depend on embed)
  ln2_k<<<2 * Tt, blk, 0, stream>>>(ENC, enc_ln1_g, enc_ln1_b, Hb,
                                    X, dec_ln1_g, dec_ln1_b, Hb2, Tt);
  gemm2<64, 128, 128, true>(stream,
      mkGDA(Hb,  BTq(0), Tt, QKVW, Dd, 64, 128, S1, 0),
      mkGDA(Hb2, BTq(2), Tt, QKVW, Dd, 64, 128, S2, 0));
  fattn_k<<<2 * attnB, fblk, 0, stream>>>(mkAB(S1), AO, mkAB(S2), AO2, attnB);
  gemm2<64, 64, 128, true>(stream,
      mkGD(AO,  BTu(0), enc_uo_b,    ENC, ENC, Tt, Dd, Dd, Dd, 64, 64, 0, 0),
      mkGD(AO2, BTu(2), dec_sa_uo_b, X,   X,   Tt, Dd, Dd, Dd, 64, 64, 0, 0));
  // enc L0 LN2 || dec L0 LN2 (dec cross-Q needs only LN2(X))
  ln2_k<<<2 * Tt, blk, 0, stream>>>(ENC, enc_ln2_g, enc_ln2_b, Hb,
                                    X, dec_ln2_g, dec_ln2_b, Hb2, Tt);
  // enc L0 FF1 || dec L0 cross-Q (S2 sa-content dead after dual attn)
  gemm2<64, 128, 128, true>(stream,
      mkGD(Hb, BT1(0), enc_ff_b1, nullptr, Fb, Tt, FFf, Dd, FFf, 64, 128, 1, 1),
      mkGDA(Hb2, BTq(4), Tt, Dd, Dd, 64, 128, S2, 0));
  gemm1<64, 64, 128, false>(stream,
      mkGD(Fb, BT2(0), enc_ff_b2, ENC, ENC, Tt, Dd, FFf, Dd, 64, 64, 0, 0));

  // ---- enc L1 full
  ln2_k<<<Tt, blk, 0, stream>>>(ENC, enc_ln1_g + Dd, enc_ln1_b + Dd, Hb,
                                ENC, enc_ln1_g + Dd, enc_ln1_b + Dd, Hb, Tt);
  gemm1<64, 128, 128, true>(stream,
      mkGDA(Hb, BTq(1), Tt, QKVW, Dd, 64, 128, S1, 0));
  fattn_k<<<attnB, fblk, 0, stream>>>(mkAB(S1), AO, mkAB(S1), AO, attnB);
  gemm1<64, 64, 128, true>(stream,
      mkGD(AO, BTu(1), enc_uo_b + Dd, ENC, ENC, Tt, Dd, Dd, Dd, 64, 64, 0, 0));
  ln2_k<<<Tt, blk, 0, stream>>>(ENC, enc_ln2_g + Dd, enc_ln2_b + Dd, Hb,
                                ENC, enc_ln2_g + Dd, enc_ln2_b + Dd, Hb, Tt);
  gemm1<64, 128, 128, true>(stream,
      mkGD(Hb, BT1(1), enc_ff_b1 + FFf, nullptr, Fb, Tt, FFf, Dd, FFf, 64, 128, 1, 1));
  gemm1<64, 64, 128, false>(stream,
      mkGD(Fb, BT2(1), enc_ff_b2 + Dd, ENC, ENC, Tt, Dd, FFf, Dd, 64, 64, 0, 0));

  // ---- enc final LN, then dec L0 cross (Q already in S2.qh/ql)
  ln2_k<<<Tt, blk, 0, stream>>>(ENC, ln_enc_g, ln_enc_b, ENCFb,
                                ENC, ln_enc_g, ln_enc_b, ENCFb, Tt);
  gemm1<64, 128, 128, true>(stream,
      mkGDA(ENCFb, BTq(4) + (size_t)Dd * Dd, Tt, 2 * Dd, Dd, 64, 128, S2, 1));
  fattn_k<<<attnB, fblk, 0, stream>>>(mkAB(S2), AO2, mkAB(S2), AO2, attnB);
  gemm1<64, 64, 128, true>(stream,
      mkGD(AO2, BTu(4), dec_ca_uo_b, X, X, Tt, Dd, Dd, Dd, 64, 64, 0, 0));
  // dec L0 ffn
  ln2_k<<<Tt, blk, 0, stream>>>(X, dec_ln3_g, dec_ln3_b, Hb,
                                X, dec_ln3_g, dec_ln3_b, Hb, Tt);
  gemm1<64, 128, 128, true>(stream,
      mkGD(Hb, BT1(2), dec_ff_b1, nullptr, Fb, Tt, FFf, Dd, FFf, 64, 128, 1, 1));
  gemm1<64, 64, 128, false>(stream,
      mkGD(Fb, BT2(2), dec_ff_b2, X, X, Tt, Dd, FFf, Dd, 64, 64, 0, 0));

  // ---- dec L1
  ln2_k<<<Tt, blk, 0, stream>>>(X, dec_ln1_g + Dd, dec_ln1_b + Dd, Hb,
                                X, dec_ln1_g + Dd, dec_ln1_b + Dd, Hb, Tt);
  gemm1<64, 128, 128, true>(stream,
      mkGDA(Hb, BTq(3), Tt, QKVW, Dd, 64, 128, S1, 0));
  fattn_k<<<attnB, fblk, 0, stream>>>(mkAB(S1), AO, mkAB(S1), AO, attnB);
  gemm1<64, 64, 128, true>(stream,
      mkGD(AO, BTu(3), dec_sa_uo_b + Dd, X, X, Tt, Dd, Dd, Dd, 64, 64, 0, 0));
  ln2_k<<<Tt, blk, 0, stream>>>(X, dec_ln2_g + Dd, dec_ln2_b + Dd, Hb,
                                X, dec_ln2_g + Dd, dec_ln2_b + Dd, Hb, Tt);
  gemm2<64, 128, 128, true>(stream,
      mkGDA(Hb,    BTq(5),                   Tt, Dd,     Dd, 64, 128, S1, 0),
      mkGDA(ENCFb, BTq(5) + (size_t)Dd * Dd, Tt, 2 * Dd, Dd, 64, 128, S1, 1));
  fattn_k<<<attnB, fblk, 0, stream>>>(mkAB(S1), AO, mkAB(S1), AO, attnB);
  gemm1<64, 64, 128, true>(stream,
      mkGD(AO, BTu(5), dec_ca_uo_b + Dd, X, X, Tt, Dd, Dd, Dd, 64, 64, 0, 0));
  ln2_k<<<Tt, blk, 0, stream>>>(X, dec_ln3_g + Dd, dec_ln3_b + Dd, Hb,
                                X, dec_ln3_g + Dd, dec_ln3_b + Dd, Hb, Tt);
  gemm1<64, 128, 128, true>(stream,
      mkGD(Hb, BT1(3), dec_ff_b1 + FFf, nullptr, Fb, Tt, FFf, Dd, FFf, 64, 128, 1, 1));
  gemm1<64, 64, 128, false>(stream,
      mkGD(Fb, BT2(3), dec_ff_b2 + Dd, X, X, Tt, Dd, FFf, Dd, 64, 64, 0, 0));

  ln2_k<<<Tt, blk, 0, stream>>>(X, ln_dec_g, ln_dec_b, Hb, X, ln_dec_g, ln_dec_b, Hb, Tt);

  // vocab head: 64x128/BK64 (24 KB LDS, ~8 blocks/CU) — best measured config
  if (!headInPrep)
    tcast_k<<<dim3(Vv / 32, Dd / 32), blk, 0, stream>>>(head_w, BThead, Dd, Vv);
  gemm1<64, 128, 64, true>(stream,
      mkGD(Hb, BThead, head_b, nullptr, out, Tt, Vv, Dd, Vv, 64, 128, 0, 0));
}